// Round 3
// baseline (268.483 us; speedup 1.0000x reference)
//
#include <hip/hip_runtime.h>
#include <hip/hip_bf16.h>

// ---------------------------------------------------------------------------
// LucasKANLayer fused: y[b,o] = sum_i sum_d L_d(tanh(x[b,i])) * C[i,o,d]
// R3: A-fragments expanded IN REGISTERS (the 16x16x32 A-frag's 8 k-elements
// are exactly the 8 Lucas values of one t) -> no As LDS, ONE barrier/step.
// BM=64 -> grid 1024 = 4 blocks/CU resident for barrier-stall overlap.
// ---------------------------------------------------------------------------

typedef __attribute__((ext_vector_type(8)))  short  short8;    // bf16x8 MFMA frag
typedef __attribute__((ext_vector_type(4)))  unsigned short ushort4v;
typedef __attribute__((ext_vector_type(8)))  unsigned short ushort8;
typedef __attribute__((ext_vector_type(4)))  float  float4v;
typedef __attribute__((ext_vector_type(4)))  unsigned int uint4v;

#define M_DIM 8192
#define I_DIM 1024
#define O_DIM 1024
#define K_DIM 8192   // I_DIM * 8
#define BM 64
#define BN 128
#define BK 64        // 8 i-values per K-step
#define NSTEP (K_DIM / BK)

// round-to-nearest-even fp32 -> bf16 bits (prep kernels)
__device__ __forceinline__ unsigned short f2bf(float f) {
    unsigned int u = __float_as_uint(f);
    u += 0x7FFFu + ((u >> 16) & 1u);
    return (unsigned short)(u >> 16);
}

// ---- prep T: T[b][i] = bf16(tanh(x[b,i])) ----
__global__ __launch_bounds__(256) void prep_t_kernel(const float* __restrict__ x,
                                                     unsigned short* __restrict__ T) {
    int idx = (blockIdx.x * 256 + threadIdx.x) * 4;
    float4v v = *(const float4v*)(x + idx);
    ushort4v o;
    o[0] = f2bf(tanhf(v[0]));
    o[1] = f2bf(tanhf(v[1]));
    o[2] = f2bf(tanhf(v[2]));
    o[3] = f2bf(tanhf(v[3]));
    *(ushort4v*)(T + idx) = o;
}

// ---- prep B: Bt[o][i*8+d] = bf16(coeffs[i][o][d]) ----
__global__ __launch_bounds__(256) void prep_b_kernel(const float* __restrict__ c,
                                                     unsigned short* __restrict__ Bt) {
    int idx = blockIdx.x * 256 + threadIdx.x;   // one (i,o)
    int i = idx >> 10;
    int o = idx & 1023;
    const float* src = c + (size_t)i * 8192 + o * 8;
    float4v lo = *(const float4v*)(src);
    float4v hi = *(const float4v*)(src + 4);
    ushort8 v;
    v[0] = f2bf(lo[0]); v[1] = f2bf(lo[1]); v[2] = f2bf(lo[2]); v[3] = f2bf(lo[3]);
    v[4] = f2bf(hi[0]); v[5] = f2bf(hi[1]); v[6] = f2bf(hi[2]); v[7] = f2bf(hi[3]);
    *(ushort8*)(Bt + (size_t)o * K_DIM + i * 8) = v;
}

// Lucas A-fragment from one bf16 t (bits in tb): {2, t, L2..L7} packed bf16x8.
// Round-half-up pack via +0x8000 and v_perm (verified R2: absmax 1.95e-3).
__device__ __forceinline__ short8 lucas_frag(unsigned int tb) {
    const float t = __uint_as_float(tb << 16);
    const float L2v = fmaf(t, t, 2.0f);
    const float L3v = fmaf(t, L2v, t);
    const float L4v = fmaf(t, L3v, L2v);
    const float L5v = fmaf(t, L4v, L3v);
    const float L6v = fmaf(t, L5v, L4v);
    const float L7v = fmaf(t, L6v, L5v);
    const unsigned int u2 = __float_as_uint(L2v) + 0x8000u;
    const unsigned int u3 = __float_as_uint(L3v) + 0x8000u;
    const unsigned int u4 = __float_as_uint(L4v) + 0x8000u;
    const unsigned int u5 = __float_as_uint(L5v) + 0x8000u;
    const unsigned int u6 = __float_as_uint(L6v) + 0x8000u;
    const unsigned int u7 = __float_as_uint(L7v) + 0x8000u;
    union { uint4v u; short8 s; } r;
    r.u[0] = 0x4000u | (tb << 16);                       // L0=2.0, L1=t
    r.u[1] = __builtin_amdgcn_perm(u3, u2, 0x07060302);  // hi16(u2)|hi16(u3)
    r.u[2] = __builtin_amdgcn_perm(u5, u4, 0x07060302);
    r.u[3] = __builtin_amdgcn_perm(u7, u6, 0x07060302);
    return r.s;
}

// ---- fused GEMM: out[m][n] = sum_k A[m][k] * Bt[n][k], A expanded in regs ----
__global__ __launch_bounds__(256, 4) void gemm_kernel(const unsigned short* __restrict__ T,
                                                      const unsigned short* __restrict__ Bt,
                                                      float* __restrict__ out) {
    __shared__ unsigned short Bs[2][BN * BK];   // 32 KB, XOR-swizzled, dbuf
    __shared__ unsigned short Ts[2][BM * 8];    // 2 KB, dbuf

    const int tid  = threadIdx.x;
    const int lane = tid & 63;
    const int wave = tid >> 6;
    const int m0 = blockIdx.x * BM;   // x = m fast: same-x blocks (share T stripe) land on same XCD
    const int n0 = blockIdx.y * BN;

    const int wm0  = (wave >> 1) * 32;   // wave tile 32 m x 64 n
    const int wn0  = (wave & 1) * 64;
    const int l16  = lane & 15;
    const int quad = lane >> 4;

    // staging lane mapping: row-sub srow, XOR-swizzled chunk
    const int srow   = lane >> 3;            // 0..7
    const int il     = lane & 7;
    const int gchunk = il ^ srow;            // global 16B chunk this lane fetches

    float4v acc[2][4];
    const float4v zero = {0.f, 0.f, 0.f, 0.f};
    #pragma unroll
    for (int a = 0; a < 2; ++a)
        #pragma unroll
        for (int b = 0; b < 4; ++b) acc[a][b] = zero;

    // ---- prologue: stage Bs[0], Ts[0] for kt=0 ----
    #pragma unroll
    for (int r = 0; r < 4; ++r) {
        const int rowb = r * 32 + wave * 8;
        const unsigned short* gB = Bt + (size_t)(n0 + rowb + srow) * K_DIM + gchunk * 8;
        __builtin_amdgcn_global_load_lds(
            (const __attribute__((address_space(1))) unsigned int*)gB,
            (__attribute__((address_space(3))) unsigned int*)&Bs[0][rowb * BK], 16, 0, 0);
    }
    if (wave == 0) {
        const unsigned short* gT = T + (size_t)(m0 + lane) * I_DIM;
        __builtin_amdgcn_global_load_lds(
            (const __attribute__((address_space(1))) unsigned int*)gT,
            (__attribute__((address_space(3))) unsigned int*)&Ts[0][0], 16, 0, 0);
    }
    __syncthreads();

    int cur = 0;
    for (int s = 0; s < NSTEP; ++s) {
        const int nxt = cur ^ 1;

        // ---- prefetch next step (drained by the end-of-step barrier) ----
        if (s + 1 < NSTEP) {
            const int kt = (s + 1) * BK;
            #pragma unroll
            for (int r = 0; r < 4; ++r) {
                const int rowb = r * 32 + wave * 8;
                const unsigned short* gB = Bt + (size_t)(n0 + rowb + srow) * K_DIM + kt + gchunk * 8;
                __builtin_amdgcn_global_load_lds(
                    (const __attribute__((address_space(1))) unsigned int*)gB,
                    (__attribute__((address_space(3))) unsigned int*)&Bs[nxt][rowb * BK], 16, 0, 0);
            }
            if (wave == 0) {
                const unsigned short* gT = T + (size_t)(m0 + lane) * I_DIM + kt / 8;
                __builtin_amdgcn_global_load_lds(
                    (const __attribute__((address_space(1))) unsigned int*)gT,
                    (__attribute__((address_space(3))) unsigned int*)&Ts[nxt][0], 16, 0, 0);
            }
        }

        // ---- t-values -> register A-frags -> MFMA ----
        unsigned int tb[2][2];
        #pragma unroll
        for (int tt = 0; tt < 2; ++tt)
            #pragma unroll
            for (int k2 = 0; k2 < 2; ++k2)
                tb[tt][k2] = Ts[cur][(wm0 + tt * 16 + l16) * 8 + (k2 * 4 + quad)];

        #pragma unroll
        for (int k2 = 0; k2 < 2; ++k2) {
            short8 af[2];
            af[0] = lucas_frag(tb[0][k2]);
            af[1] = lucas_frag(tb[1][k2]);
            short8 bfr[4];
            #pragma unroll
            for (int tn = 0; tn < 4; ++tn) {
                const int brow = wn0 + tn * 16 + l16;
                bfr[tn] = *(const short8*)&Bs[cur][brow * BK + (((k2 * 4 + quad) ^ (l16 & 7)) * 8)];
            }
            #pragma unroll
            for (int tt = 0; tt < 2; ++tt)
                #pragma unroll
                for (int tn = 0; tn < 4; ++tn)
                    acc[tt][tn] = __builtin_amdgcn_mfma_f32_16x16x32_bf16(
                        af[tt], bfr[tn], acc[tt][tn], 0, 0, 0);
        }

        __syncthreads();   // drains prefetch (vmcnt 0) + protects Bs/Ts swap
        cur = nxt;
    }

    // ---- epilogue: D[row=(lane>>4)*4+r][col=lane&15] (verified R1/R2) ----
    #pragma unroll
    for (int tt = 0; tt < 2; ++tt) {
        #pragma unroll
        for (int tn = 0; tn < 4; ++tn) {
            const int col = n0 + wn0 + tn * 16 + l16;
            #pragma unroll
            for (int r = 0; r < 4; ++r) {
                const int row = m0 + wm0 + tt * 16 + quad * 4 + r;
                out[(size_t)row * O_DIM + col] = acc[tt][tn][r];
            }
        }
    }
}

// ---- fallback (tiny workspace): direct fp32 ----
__global__ __launch_bounds__(256) void naive_kernel(const float* __restrict__ x,
                                                    const float* __restrict__ c,
                                                    float* __restrict__ out) {
    int idx = blockIdx.x * 256 + threadIdx.x;   // one (b,o)
    int b = idx >> 10;
    int o = idx & 1023;
    const float* xb = x + (size_t)b * I_DIM;
    float acc = 0.f;
    for (int i = 0; i < I_DIM; ++i) {
        float t = tanhf(xb[i]);
        float L[8];
        L[0] = 2.0f; L[1] = t;
        #pragma unroll
        for (int d = 2; d < 8; ++d) L[d] = t * L[d - 1] + L[d - 2];
        const float* cc = c + (size_t)i * 8192 + o * 8;
        #pragma unroll
        for (int d = 0; d < 8; ++d) acc += L[d] * cc[d];
    }
    out[idx] = acc;
}

extern "C" void kernel_launch(void* const* d_in, const int* in_sizes, int n_in,
                              void* d_out, int out_size, void* d_ws, size_t ws_size,
                              hipStream_t stream) {
    const float* x      = (const float*)d_in[0];
    const float* coeffs = (const float*)d_in[1];
    float* out = (float*)d_out;

    const size_t btBytes = (size_t)O_DIM * K_DIM * sizeof(unsigned short);   // 16 MiB
    const size_t tBytes  = (size_t)M_DIM * I_DIM * sizeof(unsigned short);   // 16 MiB

    if (ws_size >= btBytes + tBytes) {
        unsigned short* Bt = (unsigned short*)d_ws;
        unsigned short* T  = (unsigned short*)((char*)d_ws + btBytes);

        prep_b_kernel<<<(I_DIM * O_DIM) / 256, 256, 0, stream>>>(coeffs, Bt);
        prep_t_kernel<<<(M_DIM * I_DIM) / (4 * 256), 256, 0, stream>>>(x, T);

        dim3 grid(M_DIM / BM, O_DIM / BN);   // (128, 8) = 1024 blocks = 4/CU
        gemm_kernel<<<grid, 256, 0, stream>>>(T, Bt, out);
    } else {
        naive_kernel<<<(M_DIM * O_DIM) / 256, 256, 0, stream>>>(x, coeffs, out);
    }
}